// Round 1
// baseline (300.514 us; speedup 1.0000x reference)
//
#include <hip/hip_runtime.h>

#define B_BATCH 16
#define XLEN    320000
#define NFFT    2048
#define HOP     512
#define PADW    1024
#define NFREQ   1025
#define T_OUT   626
#define M_ROWS  2050   // 1025 real rows then 1025 imag rows
#define BM      128
#define BN      128
#define BK      64
#define MT      ((M_ROWS + BM - 1) / BM)   // 17
#define NTT     ((T_OUT + BN - 1) / BN)    // 5

typedef __bf16 bf16x8 __attribute__((ext_vector_type(8)));
typedef __bf16 bf16x4 __attribute__((ext_vector_type(4)));
typedef float  f32x4  __attribute__((ext_vector_type(4)));

// XOR swizzle: spread 16B column slots across banks (G4 fix for 128B row stride)
__device__ __forceinline__ unsigned lds_off(int row, int kbyte) {
    return (unsigned)(row * 128 + (kbyte ^ ((row & 7) << 4)));
}

__global__ __launch_bounds__(256) void stft_gemm(
    const float* __restrict__ x,
    const float* __restrict__ wre,
    const float* __restrict__ wim,
    float* __restrict__ out)
{
    __shared__ __align__(16) unsigned char ldsA[BM * BK * 2];  // 16 KB
    __shared__ __align__(16) unsigned char ldsB[BN * BK * 2];  // 16 KB

    const int tid  = threadIdx.x;
    const int lane = tid & 63;
    const int wid  = tid >> 6;
    const int wm   = wid >> 1;   // 0..1
    const int wn   = wid & 1;    // 0..1

    const int bid = blockIdx.x;
    const int b   = bid / (MT * NTT);
    const int rem = bid % (MT * NTT);
    const int mt  = rem / NTT;
    const int nt  = rem % NTT;

    const int row0 = mt * BM;
    const int col0 = nt * BN;
    const float* xb = x + (size_t)b * XLEN;

    // staging decomposition: 16 col-groups of 4 floats x 16 rows, 8 row-steps
    const int c4 = (tid & 15) * 4;   // float col within K-tile
    const int r0 = tid >> 4;         // 0..15

    f32x4 acc[4][4];
    #pragma unroll
    for (int m = 0; m < 4; ++m)
        #pragma unroll
        for (int n = 0; n < 4; ++n)
            acc[m][n] = f32x4{0.f, 0.f, 0.f, 0.f};

    const int fr = lane & 15;   // fragment row/col
    const int kq = lane >> 4;   // 0..3 (k-chunk)

    for (int k0 = 0; k0 < NFFT; k0 += BK) {
        bf16x4 sa[8], sb[8];

        // ---- A tile (weights, real rows then imag rows), fp32 -> bf16 in regs
        #pragma unroll
        for (int rr = 0; rr < 8; ++rr) {
            const int row  = rr * 16 + r0;
            const int grow = row0 + row;
            float4 v = make_float4(0.f, 0.f, 0.f, 0.f);
            if (grow < M_ROWS) {
                const float* wsrc = (grow < NFREQ)
                    ? (wre + (size_t)grow * NFFT)
                    : (wim + (size_t)(grow - NFREQ) * NFFT);
                v = *reinterpret_cast<const float4*>(wsrc + k0 + c4);
            }
            sa[rr].x = (__bf16)v.x; sa[rr].y = (__bf16)v.y;
            sa[rr].z = (__bf16)v.z; sa[rr].w = (__bf16)v.w;
        }

        // ---- B tile (frames from x with reflect padding), fp32 -> bf16
        #pragma unroll
        for (int rr = 0; rr < 8; ++rr) {
            const int trow = rr * 16 + r0;
            const int t    = col0 + trow;
            float4 v = make_float4(0.f, 0.f, 0.f, 0.f);
            if (t < T_OUT) {
                const int pos = t * HOP + k0 + c4 - PADW;
                if (pos >= 0 && pos <= XLEN - 4) {
                    v = *reinterpret_cast<const float4*>(xb + pos);
                } else {
                    float tmp[4];
                    #pragma unroll
                    for (int e = 0; e < 4; ++e) {
                        int p = pos + e;
                        p = (p < 0) ? -p : p;
                        p = (p >= XLEN) ? (2 * XLEN - 2 - p) : p;
                        tmp[e] = xb[p];
                    }
                    v = make_float4(tmp[0], tmp[1], tmp[2], tmp[3]);
                }
            }
            sb[rr].x = (__bf16)v.x; sb[rr].y = (__bf16)v.y;
            sb[rr].z = (__bf16)v.z; sb[rr].w = (__bf16)v.w;
        }

        __syncthreads();   // previous tile's reads complete

        #pragma unroll
        for (int rr = 0; rr < 8; ++rr) {
            const int row = rr * 16 + r0;
            *reinterpret_cast<bf16x4*>(ldsA + lds_off(row, c4 * 2)) = sa[rr];
            *reinterpret_cast<bf16x4*>(ldsB + lds_off(row, c4 * 2)) = sb[rr];
        }

        __syncthreads();   // writes visible

        #pragma unroll
        for (int kk = 0; kk < 2; ++kk) {
            const int kbyte = kk * 64 + kq * 16;
            bf16x8 af[4], bfv[4];
            #pragma unroll
            for (int m = 0; m < 4; ++m)
                af[m] = *reinterpret_cast<const bf16x8*>(
                    ldsA + lds_off(wm * 64 + m * 16 + fr, kbyte));
            #pragma unroll
            for (int n = 0; n < 4; ++n)
                bfv[n] = *reinterpret_cast<const bf16x8*>(
                    ldsB + lds_off(wn * 64 + n * 16 + fr, kbyte));
            #pragma unroll
            for (int m = 0; m < 4; ++m)
                #pragma unroll
                for (int n = 0; n < 4; ++n)
                    acc[m][n] = __builtin_amdgcn_mfma_f32_16x16x32_bf16(
                        af[m], bfv[n], acc[m][n], 0, 0, 0);
        }
    }

    // ---- epilogue: C/D layout col = lane&15, row = (lane>>4)*4 + j
    const size_t imag_base = (size_t)B_BATCH * NFREQ * T_OUT;
    #pragma unroll
    for (int m = 0; m < 4; ++m) {
        #pragma unroll
        for (int n = 0; n < 4; ++n) {
            #pragma unroll
            for (int j = 0; j < 4; ++j) {
                const int grow = row0 + wm * 64 + m * 16 + kq * 4 + j;
                const int gcol = col0 + wn * 64 + n * 16 + fr;
                if (grow < M_ROWS && gcol < T_OUT) {
                    size_t off;
                    if (grow < NFREQ)
                        off = ((size_t)b * NFREQ + grow) * T_OUT + gcol;
                    else
                        off = imag_base + ((size_t)b * NFREQ + (grow - NFREQ)) * T_OUT + gcol;
                    out[off] = acc[m][n][j];
                }
            }
        }
    }
}

extern "C" void kernel_launch(void* const* d_in, const int* in_sizes, int n_in,
                              void* d_out, int out_size, void* d_ws, size_t ws_size,
                              hipStream_t stream) {
    const float* x   = (const float*)d_in[0];
    const float* wre = (const float*)d_in[1];
    const float* wim = (const float*)d_in[2];
    float* out = (float*)d_out;

    const dim3 grid(B_BATCH * MT * NTT);   // 16 * 17 * 5 = 1360
    stft_gemm<<<grid, 256, 0, stream>>>(x, wre, wim, out);
}

// Round 2
// 129.460 us; speedup vs baseline: 2.3213x; 2.3213x over previous
//
#include <hip/hip_runtime.h>

#define B_BATCH 16
#define XLEN    320000
#define NFFT    2048
#define HOP     512
#define PADW    1024
#define NFREQ   1025
#define T_OUT   626
#define M_ROWS  2050            // 1025 real rows then 1025 imag rows
#define BM      128
#define BN      128
#define BK      64
#define MT      17              // ceil(2050/128) -> padded to 2176 rows
#define NTT     5               // ceil(626/128)
#define KT      32              // 2048/64

#define XPAD_LEN    322048      // XLEN + 2*PADW
#define XPAD_STRIDE 330240      // padded so B-tile overreads stay in-bounds
#define APACK_BYTES ((size_t)MT * KT * 16384)               // 8,912,896
#define XPAD_BYTES  ((size_t)B_BATCH * XPAD_STRIDE * 2)     // 10,567,680
#define WS_NEEDED   (APACK_BYTES + XPAD_BYTES)

typedef __bf16 bf16x8 __attribute__((ext_vector_type(8)));
typedef __bf16 bf16x4 __attribute__((ext_vector_type(4)));
typedef float  f32x4  __attribute__((ext_vector_type(4)));

__device__ __forceinline__ unsigned lds_off(int row, int kbyte) {
    return (unsigned)(row * 128 + (kbyte ^ ((row & 7) << 4)));
}

__device__ __forceinline__ void gload_lds16(const void* g, void* l) {
    __builtin_amdgcn_global_load_lds(
        (const __attribute__((address_space(1))) unsigned int*)g,
        (__attribute__((address_space(3))) unsigned int*)l,
        16, 0, 0);
}

// ---------------- prep A: weights fp32 -> bf16, tiled + pre-swizzled ----------------
// Layout: tile(mt,kt) = 16 KB at (mt*KT+kt)*16384 bytes; within tile byte
// row*128 + s*16 holds W[mt*128+row][kt*64 + (s^(row&7))*8 .. +8] as bf16.
__global__ __launch_bounds__(256) void prep_w(
    const float* __restrict__ wre, const float* __restrict__ wim,
    __bf16* __restrict__ apack)
{
    const int gid  = blockIdx.x * 256 + threadIdx.x;   // 557056 total
    const int slot = gid & 7;
    const int row  = (gid >> 3) & 127;
    const int kt   = (gid >> 10) & 31;
    const int mt   = gid >> 15;

    const int grow = mt * 128 + row;
    const int k    = kt * 64 + (slot ^ (row & 7)) * 8;

    bf16x8 v;
    if (grow < M_ROWS) {
        const float* src = (grow < NFREQ)
            ? (wre + (size_t)grow * NFFT + k)
            : (wim + (size_t)(grow - NFREQ) * NFFT + k);
        const float4 a = *reinterpret_cast<const float4*>(src);
        const float4 b = *reinterpret_cast<const float4*>(src + 4);
        v[0] = (__bf16)a.x; v[1] = (__bf16)a.y; v[2] = (__bf16)a.z; v[3] = (__bf16)a.w;
        v[4] = (__bf16)b.x; v[5] = (__bf16)b.y; v[6] = (__bf16)b.z; v[7] = (__bf16)b.w;
    } else {
        v = bf16x8{};
    }
    *reinterpret_cast<bf16x8*>(apack + ((size_t)(mt * KT + kt) * 8192 + row * 64 + slot * 8)) = v;
}

// ---------------- prep B: reflect-padded signal fp32 -> bf16 ----------------
__global__ __launch_bounds__(256) void prep_x(
    const float* __restrict__ x, __bf16* __restrict__ xpad)
{
    const int gid = blockIdx.x * 256 + threadIdx.x;    // 660480 total
    const int b   = gid / (XPAD_STRIDE / 8);
    const int i0  = (gid % (XPAD_STRIDE / 8)) * 8;
    const float* xb = x + (size_t)b * XLEN;

    bf16x8 v;
    const int pos0 = i0 - PADW;
    if (pos0 >= 0 && pos0 + 8 <= XLEN) {
        const float4 a = *reinterpret_cast<const float4*>(xb + pos0);
        const float4 c = *reinterpret_cast<const float4*>(xb + pos0 + 4);
        v[0] = (__bf16)a.x; v[1] = (__bf16)a.y; v[2] = (__bf16)a.z; v[3] = (__bf16)a.w;
        v[4] = (__bf16)c.x; v[5] = (__bf16)c.y; v[6] = (__bf16)c.z; v[7] = (__bf16)c.w;
    } else {
        #pragma unroll
        for (int e = 0; e < 8; ++e) {
            const int i = i0 + e;
            if (i >= XPAD_LEN) { v[e] = (__bf16)0.f; continue; }
            int p = i - PADW;
            p = (p < 0) ? -p : p;
            p = (p >= XLEN) ? (2 * XLEN - 2 - p) : p;
            v[e] = (__bf16)xb[p];
        }
    }
    *reinterpret_cast<bf16x8*>(xpad + (size_t)b * XPAD_STRIDE + i0) = v;
}

// ---------------- main GEMM: m97 structure (global_load_lds + swizzled ds_read) ----------------
__global__ __launch_bounds__(256) void stft_gemm2(
    const __bf16* __restrict__ apack,
    const __bf16* __restrict__ xpad,
    float* __restrict__ out)
{
    __shared__ __align__(16) unsigned char ldsA[16384];
    __shared__ __align__(16) unsigned char ldsB[16384];

    const int tid  = threadIdx.x;
    const int lane = tid & 63;
    const int wid  = tid >> 6;
    const int wm   = wid >> 1;
    const int wn   = wid & 1;

    const int bid = blockIdx.x;
    const int b   = bid / (MT * NTT);
    const int rem = bid % (MT * NTT);
    const int mt  = rem / NTT;
    const int nt  = rem % NTT;

    const int row0 = mt * BM;
    const int col0 = nt * BN;

    const char* atiles = (const char*)(apack + (size_t)mt * KT * 8192);
    const char* xb     = (const char*)(xpad + (size_t)b * XPAD_STRIDE);

    // B staging geometry: wave covers rows [wid*32, wid*32+32)
    const int br   = wid * 32 + (lane >> 3);     // B row this lane feeds
    const int bslt = lane & 7;
    const size_t boff_const = (size_t)(col0 + br) * 1024 + (size_t)((bslt ^ (br & 7)) * 16);

    f32x4 acc[4][4];
    #pragma unroll
    for (int m = 0; m < 4; ++m)
        #pragma unroll
        for (int n = 0; n < 4; ++n)
            acc[m][n] = f32x4{0.f, 0.f, 0.f, 0.f};

    const int fr = lane & 15;
    const int kq = lane >> 4;

    for (int kt = 0; kt < KT; ++kt) {
        // ---- stage A: contiguous pre-swizzled 16 KB tile, linear both sides
        const char* aglb = atiles + (size_t)kt * 16384 + wid * 4096 + lane * 16;
        #pragma unroll
        for (int i = 0; i < 4; ++i)
            gload_lds16(aglb + i * 1024, ldsA + wid * 4096 + i * 1024);

        // ---- stage B: per-lane global addr carries the inverse swizzle
        const char* bglb = xb + boff_const + (size_t)kt * 128;
        #pragma unroll
        for (int i = 0; i < 4; ++i)
            gload_lds16(bglb + (size_t)i * 8192, ldsB + wid * 4096 + i * 1024);

        __syncthreads();   // drain loads, make LDS visible

        #pragma unroll
        for (int kk = 0; kk < 2; ++kk) {
            const int kbyte = kk * 64 + kq * 16;
            bf16x8 af[4], bfv[4];
            #pragma unroll
            for (int m = 0; m < 4; ++m)
                af[m] = *reinterpret_cast<const bf16x8*>(
                    ldsA + lds_off(wm * 64 + m * 16 + fr, kbyte));
            #pragma unroll
            for (int n = 0; n < 4; ++n)
                bfv[n] = *reinterpret_cast<const bf16x8*>(
                    ldsB + lds_off(wn * 64 + n * 16 + fr, kbyte));
            #pragma unroll
            for (int m = 0; m < 4; ++m)
                #pragma unroll
                for (int n = 0; n < 4; ++n)
                    acc[m][n] = __builtin_amdgcn_mfma_f32_16x16x32_bf16(
                        af[m], bfv[n], acc[m][n], 0, 0, 0);
        }

        __syncthreads();   // reads done before next overwrite
    }

    const size_t imag_base = (size_t)B_BATCH * NFREQ * T_OUT;
    #pragma unroll
    for (int m = 0; m < 4; ++m) {
        #pragma unroll
        for (int n = 0; n < 4; ++n) {
            #pragma unroll
            for (int j = 0; j < 4; ++j) {
                const int grow = row0 + wm * 64 + m * 16 + kq * 4 + j;
                const int gcol = col0 + wn * 64 + n * 16 + fr;
                if (grow < M_ROWS && gcol < T_OUT) {
                    size_t off;
                    if (grow < NFREQ)
                        off = ((size_t)b * NFREQ + grow) * T_OUT + gcol;
                    else
                        off = imag_base + ((size_t)b * NFREQ + (grow - NFREQ)) * T_OUT + gcol;
                    out[off] = acc[m][n][j];
                }
            }
        }
    }
}

// ---------------- round-1 fallback (used only if ws_size too small) ----------------
__global__ __launch_bounds__(256) void stft_gemm_fb(
    const float* __restrict__ x,
    const float* __restrict__ wre,
    const float* __restrict__ wim,
    float* __restrict__ out)
{
    __shared__ __align__(16) unsigned char ldsA[BM * BK * 2];
    __shared__ __align__(16) unsigned char ldsB[BN * BK * 2];

    const int tid  = threadIdx.x;
    const int lane = tid & 63;
    const int wid  = tid >> 6;
    const int wm   = wid >> 1;
    const int wn   = wid & 1;

    const int bid = blockIdx.x;
    const int b   = bid / (MT * NTT);
    const int rem = bid % (MT * NTT);
    const int mt  = rem / NTT;
    const int nt  = rem % NTT;

    const int row0 = mt * BM;
    const int col0 = nt * BN;
    const float* xb = x + (size_t)b * XLEN;

    const int c4 = (tid & 15) * 4;
    const int r0 = tid >> 4;

    f32x4 acc[4][4];
    #pragma unroll
    for (int m = 0; m < 4; ++m)
        #pragma unroll
        for (int n = 0; n < 4; ++n)
            acc[m][n] = f32x4{0.f, 0.f, 0.f, 0.f};

    const int fr = lane & 15;
    const int kq = lane >> 4;

    for (int k0 = 0; k0 < NFFT; k0 += BK) {
        bf16x4 sa[8], sb[8];
        #pragma unroll
        for (int rr = 0; rr < 8; ++rr) {
            const int row  = rr * 16 + r0;
            const int grow = row0 + row;
            float4 v = make_float4(0.f, 0.f, 0.f, 0.f);
            if (grow < M_ROWS) {
                const float* wsrc = (grow < NFREQ)
                    ? (wre + (size_t)grow * NFFT)
                    : (wim + (size_t)(grow - NFREQ) * NFFT);
                v = *reinterpret_cast<const float4*>(wsrc + k0 + c4);
            }
            sa[rr].x = (__bf16)v.x; sa[rr].y = (__bf16)v.y;
            sa[rr].z = (__bf16)v.z; sa[rr].w = (__bf16)v.w;
        }
        #pragma unroll
        for (int rr = 0; rr < 8; ++rr) {
            const int trow = rr * 16 + r0;
            const int t    = col0 + trow;
            float4 v = make_float4(0.f, 0.f, 0.f, 0.f);
            if (t < T_OUT) {
                const int pos = t * HOP + k0 + c4 - PADW;
                if (pos >= 0 && pos <= XLEN - 4) {
                    v = *reinterpret_cast<const float4*>(xb + pos);
                } else {
                    float tmp[4];
                    #pragma unroll
                    for (int e = 0; e < 4; ++e) {
                        int p = pos + e;
                        p = (p < 0) ? -p : p;
                        p = (p >= XLEN) ? (2 * XLEN - 2 - p) : p;
                        tmp[e] = xb[p];
                    }
                    v = make_float4(tmp[0], tmp[1], tmp[2], tmp[3]);
                }
            }
            sb[rr].x = (__bf16)v.x; sb[rr].y = (__bf16)v.y;
            sb[rr].z = (__bf16)v.z; sb[rr].w = (__bf16)v.w;
        }
        __syncthreads();
        #pragma unroll
        for (int rr = 0; rr < 8; ++rr) {
            const int row = rr * 16 + r0;
            *reinterpret_cast<bf16x4*>(ldsA + lds_off(row, c4 * 2)) = sa[rr];
            *reinterpret_cast<bf16x4*>(ldsB + lds_off(row, c4 * 2)) = sb[rr];
        }
        __syncthreads();
        #pragma unroll
        for (int kk = 0; kk < 2; ++kk) {
            const int kbyte = kk * 64 + kq * 16;
            bf16x8 af[4], bfv[4];
            #pragma unroll
            for (int m = 0; m < 4; ++m)
                af[m] = *reinterpret_cast<const bf16x8*>(
                    ldsA + lds_off(wm * 64 + m * 16 + fr, kbyte));
            #pragma unroll
            for (int n = 0; n < 4; ++n)
                bfv[n] = *reinterpret_cast<const bf16x8*>(
                    ldsB + lds_off(wn * 64 + n * 16 + fr, kbyte));
            #pragma unroll
            for (int m = 0; m < 4; ++m)
                #pragma unroll
                for (int n = 0; n < 4; ++n)
                    acc[m][n] = __builtin_amdgcn_mfma_f32_16x16x32_bf16(
                        af[m], bfv[n], acc[m][n], 0, 0, 0);
        }
    }

    const size_t imag_base = (size_t)B_BATCH * NFREQ * T_OUT;
    #pragma unroll
    for (int m = 0; m < 4; ++m) {
        #pragma unroll
        for (int n = 0; n < 4; ++n) {
            #pragma unroll
            for (int j = 0; j < 4; ++j) {
                const int grow = row0 + wm * 64 + m * 16 + kq * 4 + j;
                const int gcol = col0 + wn * 64 + n * 16 + fr;
                if (grow < M_ROWS && gcol < T_OUT) {
                    size_t off;
                    if (grow < NFREQ)
                        off = ((size_t)b * NFREQ + grow) * T_OUT + gcol;
                    else
                        off = imag_base + ((size_t)b * NFREQ + (grow - NFREQ)) * T_OUT + gcol;
                    out[off] = acc[m][n][j];
                }
            }
        }
    }
}

extern "C" void kernel_launch(void* const* d_in, const int* in_sizes, int n_in,
                              void* d_out, int out_size, void* d_ws, size_t ws_size,
                              hipStream_t stream) {
    const float* x   = (const float*)d_in[0];
    const float* wre = (const float*)d_in[1];
    const float* wim = (const float*)d_in[2];
    float* out = (float*)d_out;

    if (ws_size < WS_NEEDED) {
        stft_gemm_fb<<<dim3(B_BATCH * MT * NTT), 256, 0, stream>>>(x, wre, wim, out);
        return;
    }

    __bf16* apack = (__bf16*)d_ws;
    __bf16* xpad  = (__bf16*)((char*)d_ws + APACK_BYTES);

    prep_w<<<dim3(MT * KT * 128 * 8 / 256), 256, 0, stream>>>(wre, wim, apack);
    prep_x<<<dim3(B_BATCH * (XPAD_STRIDE / 8) / 256), 256, 0, stream>>>(x, xpad);
    stft_gemm2<<<dim3(B_BATCH * MT * NTT), 256, 0, stream>>>(apack, xpad, out);
}